// Round 11
// baseline (613.063 us; speedup 1.0000x reference)
//
#include <hip/hip_runtime.h>

#define N_LAT 16384
#define N_EMB 16384
#define DIM   256
#define XQ_ELEMS (N_LAT * DIM)   // 4194304

typedef __attribute__((ext_vector_type(8))) _Float16 f16x8;
typedef __attribute__((ext_vector_type(4))) float    f32x4;

// XOR swizzle on intra-tile byte address (8KB tile = [128 rows][64 bytes])
#define SWZ(a) ((a) ^ ((((a) >> 6) & 7) << 4))

// async global->LDS, 16B/lane; LDS dest = wave-uniform base (+ lane*16 by HW)
#define GLD16(g, l) __builtin_amdgcn_global_load_lds( \
    (const __attribute__((address_space(1))) unsigned int*)(g), \
    (__attribute__((address_space(3))) unsigned int*)(l), 16, 0, 0)

#define MFMA16(a, b, c) __builtin_amdgcn_mfma_f32_16x16x32_f16((a), (b), (c), 0, 0, 0)

// ---------------- workspace layout ----------------
// [0]       float  enorm[16384]   (64 KB)
// [64K]     u64    best[16384]    (128 KB) init 0xFF
// [192K]    int    hist[16384]    (64 KB)  init 0
// [256K]    double bsum[16384]    (128 KB)
// [384K]    f16    xhi_sw (8MB) ; xlo_sw ; ehi_sw ; elo_sw  (swizzled tile-major)

// ---- split fp32 -> (hi,lo) fp16 swizzled tile-major; fused fp64 row norms ----
__global__ __launch_bounds__(256) void k_convert(const float* __restrict__ src,
                                                 char* __restrict__ hi,
                                                 char* __restrict__ lo,
                                                 float* __restrict__ norm) {
    const int gid = blockIdx.x * 256 + threadIdx.x;  // 32 threads per row
    const int row = gid >> 5, k8 = gid & 31;
    const float* s = src + (size_t)row * DIM + k8 * 8;
    float f[8];
    *reinterpret_cast<float4*>(&f[0]) = *reinterpret_cast<const float4*>(s);
    *reinterpret_cast<float4*>(&f[4]) = *reinterpret_cast<const float4*>(s + 4);
    f16x8 hv, lv;
    double nrm = 0.0;
#pragma unroll
    for (int m = 0; m < 8; ++m) {
        const _Float16 h = (_Float16)f[m];
        hv[m] = h;
        lv[m] = (_Float16)(f[m] - (float)h);
        nrm += (double)f[m] * (double)f[m];
    }
    const int dst = ((row >> 7) * 8 + (k8 >> 2)) * 8192 + SWZ((row & 127) * 64 + (k8 & 3) * 16);
    *reinterpret_cast<f16x8*>(hi + dst) = hv;
    *reinterpret_cast<f16x8*>(lo + dst) = lv;
    if (norm) {                       // rows are contiguous 32-lane groups
#pragma unroll
        for (int m = 16; m; m >>= 1) nrm += __shfl_xor(nrm, m, 64);
        if (k8 == 0) norm[row] = (float)nrm;
    }
}

// ---- fused split-fp16 MFMA GEMM + argmin ----
// B-only LDS double-buffer (32 KB); A fragments direct from global (L1/L2-hot).
// One barrier per K-step: LOADA(cur) -> STAGE(next B) -> MFMA(cur) -> barrier.
// A loads are oldest in vmcnt queue -> compiler waits vmcnt(4) for A while the
// 4 B GLD16s stay in flight across the 48-MFMA phase (~230+ cyc to land).
// All fragment offsets share one swizzle base:
//   (j*16+lr)&7 == lr&7 == (w*32+i*16+lr)&7, so SWZ folds to
//   sbase = (lr*64+lg*16) ^ ((lr&7)<<4) plus compile-time constants.
// __launch_bounds__(256,4): cap 128 VGPR -> 4 blocks/CU (LDS 4x32=128<=160KB).
__global__ __launch_bounds__(256, 4) void k_argmin(const char* __restrict__ xhi,
                                                   const char* __restrict__ xlo,
                                                   const char* __restrict__ ehi,
                                                   const char* __restrict__ elo,
                                                   const float* __restrict__ enorm,
                                                   unsigned long long* __restrict__ best) {
    __shared__ char smem[32768];      // 2 halves x {Bs_hi, Bs_lo} x 8KB
    char* const sm = smem;

    const int tid = threadIdx.x;
    const int w   = tid >> 6;         // wave 0..3 -> rows w*32..+31
    const int l   = tid & 63;
    const int lg  = l >> 4;           // k-group / D-row-group
    const int lr  = l & 15;           // A-row / B-col / D-col within frag

    const int row0 = blockIdx.x * 128;
    const int kc   = blockIdx.y;      // 0..15

    // shared swizzled fragment base (byte offset, 16B-aligned)
    const int sbase = (lr * 64 + lg * 16) ^ ((lr & 7) << 4);

    const size_t lane16 = (size_t)(w * 2048 + l * 16);
    const size_t gB0    = (size_t)kc * 8 * 65536 + lane16;   // embed chunk base
    const size_t abase  = (size_t)blockIdx.x * 65536 + (size_t)(w * 2048 + sbase);

    auto STAGE = [&](int ct_, int ks_, int half_) {          // B only: 16KB/step
        const int    o  = half_ * 16384 + w * 2048;
        const size_t gb = gB0 + (size_t)ct_ * 65536 + (size_t)ks_ * 8192;
#pragma unroll
        for (int q = 0; q < 2; ++q) {
            GLD16(ehi + gb + q * 1024, sm + o +        q * 1024);
            GLD16(elo + gb + q * 1024, sm + o + 8192 + q * 1024);
        }
    };

    unsigned long long pmin[2][4];
#pragma unroll
    for (int i = 0; i < 2; ++i)
#pragma unroll
        for (int t = 0; t < 4; ++t) pmin[i][t] = ~0ULL;

    STAGE(0, 0, 0);
    __syncthreads();                  // buf0 ready
    int half = 0;

    for (int ct = 0; ct < 8; ++ct) {
        f32x4 acc[2][8];
#pragma unroll
        for (int i = 0; i < 2; ++i)
#pragma unroll
            for (int j = 0; j < 8; ++j) acc[i][j] = (f32x4)0.0f;

#pragma unroll
        for (int ks = 0; ks < 8; ++ks) {
            // A fragments for THIS step: issued first -> oldest in vmcnt queue
            const char* ax = xhi + abase + (size_t)ks * 8192;
            const char* al_p = xlo + abase + (size_t)ks * 8192;
            const f16x8 cah0 = *reinterpret_cast<const f16x8*>(ax);
            const f16x8 cah1 = *reinterpret_cast<const f16x8*>(ax + 1024);
            const f16x8 cal0 = *reinterpret_cast<const f16x8*>(al_p);
            const f16x8 cal1 = *reinterpret_cast<const f16x8*>(al_p + 1024);

            // next-step B prefetch (lands during the MFMA phase below)
            int nks = ks + 1, nct = ct;
            if (nks == 8) { nks = 0; ++nct; }
            if (nct < 8) STAGE(nct, nks, half ^ 1);

            const int hb = half * 16384 + sbase;
#pragma unroll
            for (int j = 0; j < 8; ++j) {
                const f16x8 bh = *reinterpret_cast<const f16x8*>(sm + hb +        j * 1024);
                const f16x8 bl = *reinterpret_cast<const f16x8*>(sm + hb + 8192 + j * 1024);
                acc[0][j] = MFMA16(cah0, bh, acc[0][j]);
                acc[0][j] = MFMA16(cah0, bl, acc[0][j]);
                acc[0][j] = MFMA16(cal0, bh, acc[0][j]);
                acc[1][j] = MFMA16(cah1, bh, acc[1][j]);
                acc[1][j] = MFMA16(cah1, bl, acc[1][j]);
                acc[1][j] = MFMA16(cal1, bh, acc[1][j]);
            }
            __syncthreads();          // drains vmcnt(0): next B buf ready
            half ^= 1;
        }
        // epilogue: dist = ||e||^2 - 2*dot ; cols ascend -> first-min tie-break
        const int colbase = kc * 1024 + ct * 128;
#pragma unroll
        for (int j = 0; j < 8; ++j) {
            const int   col = colbase + j * 16 + lr;
            const float s   = enorm[col];
#pragma unroll
            for (int i = 0; i < 2; ++i)
#pragma unroll
                for (int t = 0; t < 4; ++t) {
                    const float v = fmaf(-2.0f, acc[i][j][t], s);
                    unsigned u = __float_as_uint(v);
                    u = (u & 0x80000000u) ? ~u : (u | 0x80000000u);  // monotone map
                    const unsigned long long p = ((unsigned long long)u << 32) | (unsigned)col;
                    if (p < pmin[i][t]) pmin[i][t] = p;
                }
        }
    }
    // reduce over the 16 col-lanes of each group, one atomic per row
#pragma unroll
    for (int i = 0; i < 2; ++i)
#pragma unroll
        for (int t = 0; t < 4; ++t) {
            unsigned long long p = pmin[i][t];
#pragma unroll
            for (int m = 1; m < 16; m <<= 1) {
                const unsigned long long q = __shfl_xor(p, m, 64);
                if (q < p) p = q;
            }
            if (lr == 0) {
                const int row = row0 + w * 32 + i * 16 + lg * 4 + t;
                atomicMin(&best[row], p);
            }
        }
}

// ---- gather x_q, STE output, per-row SSE, histogram, indices ----
__global__ __launch_bounds__(256) void k_gather(const float* __restrict__ x,
                                                const float* __restrict__ embed,
                                                const unsigned long long* __restrict__ best,
                                                float* __restrict__ out,
                                                int* __restrict__ hist,
                                                double* __restrict__ bsum) {
    __shared__ double partial[4];
    const int row = blockIdx.x;
    const int t   = threadIdx.x;
    const int idx = (int)(best[row] & 0xFFFFFFFFULL);
    const float e  = embed[(size_t)idx * DIM + t];
    const float xv = x[(size_t)row * DIM + t];
    const float d  = e - xv;
    out[(size_t)row * DIM + t] = xv + d;     // x + (x_q - x): matches STE rounding
    double sq = (double)d * (double)d;
#pragma unroll
    for (int m = 32; m; m >>= 1) sq += __shfl_xor(sq, m, 64);
    const int lane = t & 63, wv = t >> 6;
    if (lane == 0) partial[wv] = sq;
    __syncthreads();
    if (t == 0) {
        bsum[row] = partial[0] + partial[1] + partial[2] + partial[3];
        atomicAdd(&hist[idx], 1);
        out[XQ_ELEMS + 2 + row] = (float)idx;
    }
}

__global__ __launch_bounds__(256) void k_final(const int* __restrict__ hist,
                                               const double* __restrict__ bsum,
                                               float* __restrict__ out) {
    __shared__ int    cpart[4];
    __shared__ double spart[4];
    const int t = threadIdx.x;
    int cnt = 0; double s = 0.0;
    for (int i = t; i < N_EMB; i += 256) {
        cnt += (hist[i] == 0) ? 1 : 0;
        s += bsum[i];
    }
#pragma unroll
    for (int m = 32; m; m >>= 1) {
        cnt += __shfl_xor(cnt, m, 64);
        s   += __shfl_xor(s, m, 64);
    }
    const int lane = t & 63, wv = t >> 6;
    if (lane == 0) { cpart[wv] = cnt; spart[wv] = s; }
    __syncthreads();
    if (t == 0) {
        const double sse = spart[0] + spart[1] + spart[2] + spart[3];
        out[XQ_ELEMS + 0] = (float)(1.25 * sse / (double)XQ_ELEMS);
        out[XQ_ELEMS + 1] = (float)(cpart[0] + cpart[1] + cpart[2] + cpart[3]);
    }
}

extern "C" void kernel_launch(void* const* d_in, const int* in_sizes, int n_in,
                              void* d_out, int out_size, void* d_ws, size_t ws_size,
                              hipStream_t stream) {
    const float* x     = (const float*)d_in[0];
    const float* embed = (const float*)d_in[1];
    float* out = (float*)d_out;

    char* ws = (char*)d_ws;
    float*              enorm = (float*)(ws + 0);
    unsigned long long* best  = (unsigned long long*)(ws + 65536);
    int*                hist  = (int*)(ws + 196608);
    double*             bsum  = (double*)(ws + 262144);
    char*               xhi   = ws + 393216;
    char*               xlo   = xhi + 8388608;
    char*               ehi   = xlo + 8388608;
    char*               elo   = ehi + 8388608;

    hipMemsetAsync(best, 0xFF, N_LAT * sizeof(unsigned long long), stream);
    hipMemsetAsync(hist, 0x00, N_EMB * sizeof(int), stream);

    k_convert<<<2048, 256, 0, stream>>>(x, xhi, xlo, nullptr);
    k_convert<<<2048, 256, 0, stream>>>(embed, ehi, elo, enorm);
    k_argmin <<<dim3(128, 16), 256, 0, stream>>>(xhi, xlo, ehi, elo, enorm, best);
    k_gather <<<N_LAT, 256, 0, stream>>>(x, embed, best, out, hist, bsum);
    k_final  <<<1, 256, 0, stream>>>(hist, bsum, out);
}

// Round 12
// 559.156 us; speedup vs baseline: 1.0964x; 1.0964x over previous
//
#include <hip/hip_runtime.h>

#define N_LAT 16384
#define N_EMB 16384
#define DIM   256
#define XQ_ELEMS (N_LAT * DIM)   // 4194304

typedef __attribute__((ext_vector_type(8))) _Float16 f16x8;
typedef __attribute__((ext_vector_type(4))) float    f32x4;

// XOR swizzle on intra-tile byte address (8KB tile = [128 rows][64 bytes])
#define SWZ(a) ((a) ^ ((((a) >> 6) & 7) << 4))

// async global->LDS, 16B/lane; LDS dest = wave-uniform base (+ lane*16 by HW)
#define GLD16(g, l) __builtin_amdgcn_global_load_lds( \
    (const __attribute__((address_space(1))) unsigned int*)(g), \
    (__attribute__((address_space(3))) unsigned int*)(l), 16, 0, 0)

#define MFMA16(a, b, c) __builtin_amdgcn_mfma_f32_16x16x32_f16((a), (b), (c), 0, 0, 0)

// ---------------- workspace layout ----------------
// [0]       float  enorm[16384]   (64 KB)
// [64K]     u64    best[16384]    (128 KB) init 0xFF
// [192K]    int    hist[16384]    (64 KB)  init 0
// [256K]    double bsum[16384]    (128 KB)
// [384K]    f16    xhi_sw (8MB) ; xlo_sw ; ehi_sw ; elo_sw  (swizzled tile-major)

// ---- split fp32 -> (hi,lo) fp16 swizzled tile-major; fused fp64 row norms ----
__global__ __launch_bounds__(256) void k_convert(const float* __restrict__ src,
                                                 char* __restrict__ hi,
                                                 char* __restrict__ lo,
                                                 float* __restrict__ norm) {
    const int gid = blockIdx.x * 256 + threadIdx.x;  // 32 threads per row
    const int row = gid >> 5, k8 = gid & 31;
    const float* s = src + (size_t)row * DIM + k8 * 8;
    float f[8];
    *reinterpret_cast<float4*>(&f[0]) = *reinterpret_cast<const float4*>(s);
    *reinterpret_cast<float4*>(&f[4]) = *reinterpret_cast<const float4*>(s + 4);
    f16x8 hv, lv;
    double nrm = 0.0;
#pragma unroll
    for (int m = 0; m < 8; ++m) {
        const _Float16 h = (_Float16)f[m];
        hv[m] = h;
        lv[m] = (_Float16)(f[m] - (float)h);
        nrm += (double)f[m] * (double)f[m];
    }
    const int dst = ((row >> 7) * 8 + (k8 >> 2)) * 8192 + SWZ((row & 127) * 64 + (k8 & 3) * 16);
    *reinterpret_cast<f16x8*>(hi + dst) = hv;
    *reinterpret_cast<f16x8*>(lo + dst) = lv;
    if (norm) {                       // rows are contiguous 32-lane groups
#pragma unroll
        for (int m = 16; m; m >>= 1) nrm += __shfl_xor(nrm, m, 64);
        if (k8 == 0) norm[row] = (float)nrm;
    }
}

// ---- fused split-fp16 MFMA GEMM + argmin ----
// B-only LDS double-buffer (32 KB); A fragments direct from global (L1/L2-hot).
// One barrier per K-step: LOADA(cur) -> STAGE(next B) -> MFMA(cur) -> barrier.
// All fragment offsets share one swizzle base:
//   (j*16+lr)&7 == lr&7 == (w*32+i*16+lr)&7, so SWZ folds to
//   sbase = (lr*64+lg*16) ^ ((lr&7)<<4) plus compile-time constants.
// NO min-waves pin: this compiler budgets ~256/w arch-VGPRs for
// __launch_bounds__(256,w) (R2: w=3 -> 84, R11: w=4 -> 64) -> acc spills.
// Designed live set ~120 VGPR; let the allocator land naturally.
__global__ __launch_bounds__(256) void k_argmin(const char* __restrict__ xhi,
                                                const char* __restrict__ xlo,
                                                const char* __restrict__ ehi,
                                                const char* __restrict__ elo,
                                                const float* __restrict__ enorm,
                                                unsigned long long* __restrict__ best) {
    __shared__ char smem[32768];      // 2 halves x {Bs_hi, Bs_lo} x 8KB
    char* const sm = smem;

    const int tid = threadIdx.x;
    const int w   = tid >> 6;         // wave 0..3 -> rows w*32..+31
    const int l   = tid & 63;
    const int lg  = l >> 4;           // k-group / D-row-group
    const int lr  = l & 15;           // A-row / B-col / D-col within frag

    const int row0 = blockIdx.x * 128;
    const int kc   = blockIdx.y;      // 0..15

    // shared swizzled fragment base (byte offset, 16B-aligned)
    const int sbase = (lr * 64 + lg * 16) ^ ((lr & 7) << 4);

    const size_t lane16 = (size_t)(w * 2048 + l * 16);
    const size_t gB0    = (size_t)kc * 8 * 65536 + lane16;   // embed chunk base
    const size_t abase  = (size_t)blockIdx.x * 65536 + (size_t)(w * 2048 + sbase);

    auto STAGE = [&](int ct_, int ks_, int half_) {          // B only: 16KB/step
        const int    o  = half_ * 16384 + w * 2048;
        const size_t gb = gB0 + (size_t)ct_ * 65536 + (size_t)ks_ * 8192;
#pragma unroll
        for (int q = 0; q < 2; ++q) {
            GLD16(ehi + gb + q * 1024, sm + o +        q * 1024);
            GLD16(elo + gb + q * 1024, sm + o + 8192 + q * 1024);
        }
    };

    unsigned long long pmin[2][4];
#pragma unroll
    for (int i = 0; i < 2; ++i)
#pragma unroll
        for (int t = 0; t < 4; ++t) pmin[i][t] = ~0ULL;

    STAGE(0, 0, 0);
    __syncthreads();                  // buf0 ready
    int half = 0;

    for (int ct = 0; ct < 8; ++ct) {
        f32x4 acc[2][8];
#pragma unroll
        for (int i = 0; i < 2; ++i)
#pragma unroll
            for (int j = 0; j < 8; ++j) acc[i][j] = (f32x4)0.0f;

#pragma unroll
        for (int ks = 0; ks < 8; ++ks) {
            // A fragments for THIS step: issued first -> oldest in vmcnt queue
            const char* ax = xhi + abase + (size_t)ks * 8192;
            const char* al_p = xlo + abase + (size_t)ks * 8192;
            const f16x8 cah0 = *reinterpret_cast<const f16x8*>(ax);
            const f16x8 cah1 = *reinterpret_cast<const f16x8*>(ax + 1024);
            const f16x8 cal0 = *reinterpret_cast<const f16x8*>(al_p);
            const f16x8 cal1 = *reinterpret_cast<const f16x8*>(al_p + 1024);

            // next-step B prefetch (lands during the MFMA phase below)
            int nks = ks + 1, nct = ct;
            if (nks == 8) { nks = 0; ++nct; }
            if (nct < 8) STAGE(nct, nks, half ^ 1);

            const int hb = half * 16384 + sbase;
#pragma unroll
            for (int j = 0; j < 8; ++j) {
                const f16x8 bh = *reinterpret_cast<const f16x8*>(sm + hb +        j * 1024);
                const f16x8 bl = *reinterpret_cast<const f16x8*>(sm + hb + 8192 + j * 1024);
                acc[0][j] = MFMA16(cah0, bh, acc[0][j]);
                acc[0][j] = MFMA16(cah0, bl, acc[0][j]);
                acc[0][j] = MFMA16(cal0, bh, acc[0][j]);
                acc[1][j] = MFMA16(cah1, bh, acc[1][j]);
                acc[1][j] = MFMA16(cah1, bl, acc[1][j]);
                acc[1][j] = MFMA16(cal1, bh, acc[1][j]);
            }
            __syncthreads();          // drains vmcnt(0): next B buf ready
            half ^= 1;
        }
        // epilogue: dist = ||e||^2 - 2*dot ; cols ascend -> first-min tie-break
        const int colbase = kc * 1024 + ct * 128;
#pragma unroll
        for (int j = 0; j < 8; ++j) {
            const int   col = colbase + j * 16 + lr;
            const float s   = enorm[col];
#pragma unroll
            for (int i = 0; i < 2; ++i)
#pragma unroll
                for (int t = 0; t < 4; ++t) {
                    const float v = fmaf(-2.0f, acc[i][j][t], s);
                    unsigned u = __float_as_uint(v);
                    u = (u & 0x80000000u) ? ~u : (u | 0x80000000u);  // monotone map
                    const unsigned long long p = ((unsigned long long)u << 32) | (unsigned)col;
                    if (p < pmin[i][t]) pmin[i][t] = p;
                }
        }
    }
    // reduce over the 16 col-lanes of each group, one atomic per row
#pragma unroll
    for (int i = 0; i < 2; ++i)
#pragma unroll
        for (int t = 0; t < 4; ++t) {
            unsigned long long p = pmin[i][t];
#pragma unroll
            for (int m = 1; m < 16; m <<= 1) {
                const unsigned long long q = __shfl_xor(p, m, 64);
                if (q < p) p = q;
            }
            if (lr == 0) {
                const int row = row0 + w * 32 + i * 16 + lg * 4 + t;
                atomicMin(&best[row], p);
            }
        }
}

// ---- gather x_q, STE output, per-row SSE, histogram, indices ----
__global__ __launch_bounds__(256) void k_gather(const float* __restrict__ x,
                                                const float* __restrict__ embed,
                                                const unsigned long long* __restrict__ best,
                                                float* __restrict__ out,
                                                int* __restrict__ hist,
                                                double* __restrict__ bsum) {
    __shared__ double partial[4];
    const int row = blockIdx.x;
    const int t   = threadIdx.x;
    const int idx = (int)(best[row] & 0xFFFFFFFFULL);
    const float e  = embed[(size_t)idx * DIM + t];
    const float xv = x[(size_t)row * DIM + t];
    const float d  = e - xv;
    out[(size_t)row * DIM + t] = xv + d;     // x + (x_q - x): matches STE rounding
    double sq = (double)d * (double)d;
#pragma unroll
    for (int m = 32; m; m >>= 1) sq += __shfl_xor(sq, m, 64);
    const int lane = t & 63, wv = t >> 6;
    if (lane == 0) partial[wv] = sq;
    __syncthreads();
    if (t == 0) {
        bsum[row] = partial[0] + partial[1] + partial[2] + partial[3];
        atomicAdd(&hist[idx], 1);
        out[XQ_ELEMS + 2 + row] = (float)idx;
    }
}

__global__ __launch_bounds__(256) void k_final(const int* __restrict__ hist,
                                               const double* __restrict__ bsum,
                                               float* __restrict__ out) {
    __shared__ int    cpart[4];
    __shared__ double spart[4];
    const int t = threadIdx.x;
    int cnt = 0; double s = 0.0;
    for (int i = t; i < N_EMB; i += 256) {
        cnt += (hist[i] == 0) ? 1 : 0;
        s += bsum[i];
    }
#pragma unroll
    for (int m = 32; m; m >>= 1) {
        cnt += __shfl_xor(cnt, m, 64);
        s   += __shfl_xor(s, m, 64);
    }
    const int lane = t & 63, wv = t >> 6;
    if (lane == 0) { cpart[wv] = cnt; spart[wv] = s; }
    __syncthreads();
    if (t == 0) {
        const double sse = spart[0] + spart[1] + spart[2] + spart[3];
        out[XQ_ELEMS + 0] = (float)(1.25 * sse / (double)XQ_ELEMS);
        out[XQ_ELEMS + 1] = (float)(cpart[0] + cpart[1] + cpart[2] + cpart[3]);
    }
}

extern "C" void kernel_launch(void* const* d_in, const int* in_sizes, int n_in,
                              void* d_out, int out_size, void* d_ws, size_t ws_size,
                              hipStream_t stream) {
    const float* x     = (const float*)d_in[0];
    const float* embed = (const float*)d_in[1];
    float* out = (float*)d_out;

    char* ws = (char*)d_ws;
    float*              enorm = (float*)(ws + 0);
    unsigned long long* best  = (unsigned long long*)(ws + 65536);
    int*                hist  = (int*)(ws + 196608);
    double*             bsum  = (double*)(ws + 262144);
    char*               xhi   = ws + 393216;
    char*               xlo   = xhi + 8388608;
    char*               ehi   = xlo + 8388608;
    char*               elo   = ehi + 8388608;

    hipMemsetAsync(best, 0xFF, N_LAT * sizeof(unsigned long long), stream);
    hipMemsetAsync(hist, 0x00, N_EMB * sizeof(int), stream);

    k_convert<<<2048, 256, 0, stream>>>(x, xhi, xlo, nullptr);
    k_convert<<<2048, 256, 0, stream>>>(embed, ehi, elo, enorm);
    k_argmin <<<dim3(128, 16), 256, 0, stream>>>(xhi, xlo, ehi, elo, enorm, best);
    k_gather <<<N_LAT, 256, 0, stream>>>(x, embed, best, out, hist, bsum);
    k_final  <<<1, 256, 0, stream>>>(hist, bsum, out);
}